// Round 6
// baseline (119.835 us; speedup 1.0000x reference)
//
#include <hip/hip_runtime.h>

#define BIG 1e9f
#define CALIB_REPEATS 16   // calibration: dur_us ≈ base + 15 * (one-DP-pass time)

// ---- asm macros -----------------------------------------------------------
// RD(W): advance per-lane diag counter ik (= k - lane), clamp row to [0,63],
//        form LDS byte addr = row*256 + (base + lane*4), issue ds_read_b32.
#define RD(W) \
    "v_add_u32 %[ik], 1, %[ik]\n\t" \
    "v_med3_i32 %[ic], %[ik], 0, 63\n\t" \
    "v_lshl_add_u32 %[ad], %[ic], 8, %[sb]\n\t" \
    "ds_read_b32 " W ", %[ad]\n\t"

// CMP(W,XN,XO): allow 12 reads outstanding (oldest = this step's w is done),
//               x = wave_shr:1(e) with lane0 <- BIG, e = min3(l,u,d) + w.
#define CMP(W, XN, XO) \
    "s_waitcnt lgkmcnt(12)\n\t" \
    "v_mov_b32 " XN ", %[vbig]\n\t" \
    "v_mov_b32_dpp " XN ", %[e] wave_shr:1 row_mask:0xf bank_mask:0xf\n\t" \
    "v_min3_f32 %[tp], " XN ", %[e], " XO "\n\t" \
    "v_add_f32 %[e], %[tp], " W "\n\t"

#define SLOT(WISS, WCON, XN, XO) RD(WISS) CMP(WCON, XN, XO)

// One 64-lane wave per sample; anti-diagonal sweep with potential transform
// e[v] = d[v] + img[v]/2:  e[v] = img[v] + min3(e_left, e_up, e_diag).
// CALIBRATION BUILD: the full DP pass runs CALIB_REPEATS times (identical
// result each time) so the kernel's own duration/counters become observable
// in the rocprof top-5 and L (per-pass time) is recoverable from dur_us.
__global__ __launch_bounds__(128) void dp_diag_kernel(const float* __restrict__ img,
                                                      float* __restrict__ out, int B) {
    __shared__ __align__(16) float smem[2][4096];   // 16 KB per wave, wave-private
    const int lane = threadIdx.x & 63;
    const int wave = threadIdx.x >> 6;
    const int b = (blockIdx.x << 1) + wave;
    if (b >= B) return;                // uniform per wave; no block barrier used

    float* s = smem[wave];
    {   // coalesced float4 staging, row-major s[i*64+j]
        const float4* g4 = (const float4*)(img + ((size_t)b << 12));
        float4* s4 = (float4*)s;
        #pragma unroll
        for (int t = 0; t < 16; ++t)
            s4[(t << 6) + lane] = g4[(t << 6) + lane];
    }
    // no __syncthreads: each wave reads only its own region; same-wave DS ops
    // complete in order; the first lgkmcnt(12) drains the staging writes.

    float e = 0.0f;
    float x0, x1;
    float w0 = 0, w1 = 0, w2 = 0, w3 = 0, w4 = 0, w5 = 0, w6 = 0,
          w7 = 0, w8 = 0, w9 = 0, w10 = 0, w11 = 0, w12 = 0, w13 = 0;
    int ik, ic = 0; unsigned ad = 0; float tp = 0;
    const float    vbig  = BIG;
    const unsigned sbase = (unsigned)(uintptr_t)s + ((unsigned)lane << 2);

    #pragma unroll 1
    for (int rep = 0; rep < CALIB_REPEATS; ++rep) {
        // diag k=0 state (re-initialized every repeat)
        e  = (lane == 0) ? 0.5f * s[0] : BIG;
        x0 = BIG; x1 = BIG;
        ik = -lane;

        // prologue: issue reads for diagonals k = 1..12 into w1..w12
        asm volatile(
            RD("%[w1]") RD("%[w2]") RD("%[w3]") RD("%[w4]") RD("%[w5]") RD("%[w6]")
            RD("%[w7]") RD("%[w8]") RD("%[w9]") RD("%[w10]") RD("%[w11]") RD("%[w12]")
            "s_nop 2\n\t"
            : [ik]"+v"(ik), [ic]"+v"(ic), [ad]"+v"(ad),
              [w1]"+v"(w1), [w2]"+v"(w2), [w3]"+v"(w3), [w4]"+v"(w4),
              [w5]"+v"(w5), [w6]"+v"(w6), [w7]"+v"(w7), [w8]"+v"(w8),
              [w9]"+v"(w9), [w10]"+v"(w10), [w11]"+v"(w11), [w12]"+v"(w12)
            : [sb]"v"(sbase)
            : "memory");

        // body: 9 x 14 slots = steps k = 1..126; slot issues read k+12,
        // consumes the read from 12 slots ago; x0/x1 alternate (diag term).
        #pragma unroll 1
        for (int it = 0; it < 9; ++it) {
            asm volatile(
                SLOT("%[w13]", "%[w1]",  "%[x0]", "%[x1]")
                SLOT("%[w0]",  "%[w2]",  "%[x1]", "%[x0]")
                SLOT("%[w1]",  "%[w3]",  "%[x0]", "%[x1]")
                SLOT("%[w2]",  "%[w4]",  "%[x1]", "%[x0]")
                SLOT("%[w3]",  "%[w5]",  "%[x0]", "%[x1]")
                SLOT("%[w4]",  "%[w6]",  "%[x1]", "%[x0]")
                SLOT("%[w5]",  "%[w7]",  "%[x0]", "%[x1]")
                SLOT("%[w6]",  "%[w8]",  "%[x1]", "%[x0]")
                SLOT("%[w7]",  "%[w9]",  "%[x0]", "%[x1]")
                SLOT("%[w8]",  "%[w10]", "%[x1]", "%[x0]")
                SLOT("%[w9]",  "%[w11]", "%[x0]", "%[x1]")
                SLOT("%[w10]", "%[w12]", "%[x1]", "%[x0]")
                SLOT("%[w11]", "%[w13]", "%[x0]", "%[x1]")
                SLOT("%[w12]", "%[w0]",  "%[x1]", "%[x0]")
                : [e]"+v"(e), [x0]"+v"(x0), [x1]"+v"(x1), [tp]"+v"(tp),
                  [ik]"+v"(ik), [ic]"+v"(ic), [ad]"+v"(ad),
                  [w0]"+v"(w0), [w1]"+v"(w1), [w2]"+v"(w2), [w3]"+v"(w3),
                  [w4]"+v"(w4), [w5]"+v"(w5), [w6]"+v"(w6), [w7]"+v"(w7),
                  [w8]"+v"(w8), [w9]"+v"(w9), [w10]"+v"(w10), [w11]"+v"(w11),
                  [w12]"+v"(w12), [w13]"+v"(w13)
                : [sb]"v"(sbase), [vbig]"v"(vbig)
                : "memory");
        }
        asm volatile("s_waitcnt lgkmcnt(0)\n\t" ::: "memory");  // drain ring
    }

    if (lane == 63) out[b] = e - 0.5f * s[4095];  // d[63][63]
}

extern "C" void kernel_launch(void* const* d_in, const int* in_sizes, int n_in,
                              void* d_out, int out_size, void* d_ws, size_t ws_size,
                              hipStream_t stream) {
    const float* img = (const float*)d_in[0];
    float* out = (float*)d_out;
    const int B = out_size;                  // 2048
    const int threads = 128;                 // 2 waves (samples) per block
    const int grid = (B + 1) / 2;
    dp_diag_kernel<<<grid, threads, 0, stream>>>(img, out, B);
}

// Round 7
// 71.638 us; speedup vs baseline: 1.6728x; 1.6728x over previous
//
#include <hip/hip_runtime.h>

#define BIG 1e9f

// ---- asm macros -----------------------------------------------------------
// RD(W): advance per-lane diag counter ik (= k - lane), clamp row to [0,63],
//        form LDS byte addr = row*256 + (base + lane*4), issue ds_read_b32.
#define RD(W) \
    "v_add_u32 %[ik], 1, %[ik]\n\t" \
    "v_med3_i32 %[ic], %[ik], 0, 63\n\t" \
    "v_lshl_add_u32 %[ad], %[ic], 8, %[sb]\n\t" \
    "ds_read_b32 " W ", %[ad]\n\t"

// CMP(W,XN,XO): allow 12 ds_reads outstanding (oldest = this step's w done),
//               x = wave_shr:1(e) with lane0 <- BIG, e = min3(l,u,d) + w.
#define CMP(W, XN, XO) \
    "s_waitcnt lgkmcnt(12)\n\t" \
    "v_mov_b32 " XN ", %[vbig]\n\t" \
    "v_mov_b32_dpp " XN ", %[e] wave_shr:1 row_mask:0xf bank_mask:0xf\n\t" \
    "v_min3_f32 %[tp], " XN ", %[e], " XO "\n\t" \
    "v_add_f32 %[e], %[tp], " W "\n\t"

#define SLOT(WISS, WCON, XN, XO) RD(WISS) CMP(WCON, XN, XO)

// One asm statement = 14 DP slots (k advances by 14). Slot issues the read
// for diag k+12 and consumes the read from 12 slots ago; x0/x1 alternate.
#define BODY14 \
    asm volatile( \
        SLOT("%[w13]", "%[w1]",  "%[x0]", "%[x1]") \
        SLOT("%[w0]",  "%[w2]",  "%[x1]", "%[x0]") \
        SLOT("%[w1]",  "%[w3]",  "%[x0]", "%[x1]") \
        SLOT("%[w2]",  "%[w4]",  "%[x1]", "%[x0]") \
        SLOT("%[w3]",  "%[w5]",  "%[x0]", "%[x1]") \
        SLOT("%[w4]",  "%[w6]",  "%[x1]", "%[x0]") \
        SLOT("%[w5]",  "%[w7]",  "%[x0]", "%[x1]") \
        SLOT("%[w6]",  "%[w8]",  "%[x1]", "%[x0]") \
        SLOT("%[w7]",  "%[w9]",  "%[x0]", "%[x1]") \
        SLOT("%[w8]",  "%[w10]", "%[x1]", "%[x0]") \
        SLOT("%[w9]",  "%[w11]", "%[x0]", "%[x1]") \
        SLOT("%[w10]", "%[w12]", "%[x1]", "%[x0]") \
        SLOT("%[w11]", "%[w13]", "%[x0]", "%[x1]") \
        SLOT("%[w12]", "%[w0]",  "%[x1]", "%[x0]") \
        : [e]"+v"(e), [x0]"+v"(x0), [x1]"+v"(x1), [tp]"+v"(tp), \
          [ik]"+v"(ik), [ic]"+v"(ic), [ad]"+v"(ad), \
          [w0]"+v"(w0), [w1]"+v"(w1), [w2]"+v"(w2), [w3]"+v"(w3), \
          [w4]"+v"(w4), [w5]"+v"(w5), [w6]"+v"(w6), [w7]"+v"(w7), \
          [w8]"+v"(w8), [w9]"+v"(w9), [w10]"+v"(w10), [w11]"+v"(w11), \
          [w12]"+v"(w12), [w13]"+v"(w13) \
        : [sb]"v"(sbase), [vbig]"v"(vbig) \
        : "memory")

// One 64-lane wave per sample; lane j owns column j; anti-diagonal sweep with
// potential transform e[v] = d[v] + img[v]/2:
//   e[v] = img[v] + min3(e_left, e_up, e_diag);  out = e_final - img[63][63]/2.
// Staging: 16x global_load_lds dwordx4 (direct HBM->LDS, no VGPR roundtrip,
// all 16 in flight). Loads retire in issue order (4 rows each), so counted
// s_waitcnt vmcnt(N) lets the DP start after the first 4 transfers: each
// 14-slot block is gated on exactly the rows its 12-ahead ds_reads can touch.
__global__ __launch_bounds__(128) void dp_diag_kernel(const float* __restrict__ img,
                                                      float* __restrict__ out, int B) {
    __shared__ __align__(16) float smem[2][4096];   // 16 KB per wave, wave-private
    const int lane = threadIdx.x & 63;
    const int wave = threadIdx.x >> 6;
    const int b = (blockIdx.x << 1) + wave;
    if (b >= B) return;                // uniform per wave; no block barrier used

    float* s = smem[wave];
    {   // async staging: chunk t = rows 4t..4t+3; lane covers 16 B at lane*4 floats
        const float* g = img + ((size_t)b << 12) + (lane << 2);
        #pragma unroll
        for (int t = 0; t < 16; ++t)
            __builtin_amdgcn_global_load_lds(
                (const __attribute__((address_space(1))) void*)(g + (t << 8)),
                (__attribute__((address_space(3))) void*)(s + (t << 8)),
                16, 0, 0);
    }
    asm volatile("s_waitcnt vmcnt(12)\n\t" ::: "memory");  // t=0..3 done: rows 0..15

    float e  = (lane == 0) ? 0.5f * s[0] : BIG;   // diag k=0 state
    float x0 = BIG, x1 = BIG;                     // rotating shr1 regs (diag term)
    float w0 = 0, w1 = 0, w2 = 0, w3 = 0, w4 = 0, w5 = 0, w6 = 0,
          w7 = 0, w8 = 0, w9 = 0, w10 = 0, w11 = 0, w12 = 0, w13 = 0;
    int ik = -lane;                               // k - lane, pre-first-increment
    int ic = 0; unsigned ad = 0; float tp = 0;
    const float    vbig  = BIG;
    const unsigned sbase = (unsigned)(uintptr_t)s + ((unsigned)lane << 2);

    // prologue: issue ds_reads for diagonals k = 1..12 (rows <= 12) into w1..w12
    asm volatile(
        RD("%[w1]") RD("%[w2]") RD("%[w3]") RD("%[w4]") RD("%[w5]") RD("%[w6]")
        RD("%[w7]") RD("%[w8]") RD("%[w9]") RD("%[w10]") RD("%[w11]") RD("%[w12]")
        "s_nop 2\n\t"
        : [ik]"+v"(ik), [ic]"+v"(ic), [ad]"+v"(ad),
          [w1]"+v"(w1), [w2]"+v"(w2), [w3]"+v"(w3), [w4]"+v"(w4),
          [w5]"+v"(w5), [w6]"+v"(w6), [w7]"+v"(w7), [w8]"+v"(w8),
          [w9]"+v"(w9), [w10]"+v"(w10), [w11]"+v"(w11), [w12]"+v"(w12)
        : [sb]"v"(sbase)
        : "memory");

    // body blocks 1..4 gated on staging progress (reads reach diag k+12):
    asm volatile("s_waitcnt vmcnt(9)\n\t" ::: "memory");  // rows<=27 (reads k<=26)
    BODY14;                                               // k = 1..14
    asm volatile("s_waitcnt vmcnt(5)\n\t" ::: "memory");  // rows<=43 (reads k<=40)
    BODY14;                                               // k = 15..28
    asm volatile("s_waitcnt vmcnt(2)\n\t" ::: "memory");  // rows<=55 (reads k<=54)
    BODY14;                                               // k = 29..42
    asm volatile("s_waitcnt vmcnt(0)\n\t" ::: "memory");  // all rows resident
    BODY14;                                               // k = 43..56
    #pragma unroll 1
    for (int it = 0; it < 5; ++it)                        // k = 57..126
        BODY14;
    asm volatile("s_waitcnt lgkmcnt(0)\n\t" ::: "memory"); // drain 12 dangling reads

    if (lane == 63) out[b] = e - 0.5f * s[4095];  // d[63][63]
}

extern "C" void kernel_launch(void* const* d_in, const int* in_sizes, int n_in,
                              void* d_out, int out_size, void* d_ws, size_t ws_size,
                              hipStream_t stream) {
    const float* img = (const float*)d_in[0];
    float* out = (float*)d_out;
    const int B = out_size;                  // 2048
    const int threads = 128;                 // 2 waves (samples) per block
    const int grid = (B + 1) / 2;
    dp_diag_kernel<<<grid, threads, 0, stream>>>(img, out, B);
}

// Round 8
// 70.560 us; speedup vs baseline: 1.6983x; 1.0153x over previous
//
#include <hip/hip_runtime.h>

#define BIG 1e9f

// ---- asm macros -----------------------------------------------------------
// RD2(W): running unclamped LDS byte addr au += 256 (next row); clamp to
//         [row0, row63] with one med3 (sb = base+lane*4, hi = sb+63*256);
//         issue ds_read_b32 for diag k+12.
#define RD2(W) \
    "v_add_u32 %[au], 0x100, %[au]\n\t" \
    "v_med3_i32 %[ad], %[au], %[sb], %[hi]\n\t" \
    "ds_read_b32 " W ", %[ad]\n\t"

// CM2(W,XW,XS): x = wave_shr:1(e). No bound_ctrl => lane 0 dest is PRESERVED,
// and since XW/XS are only ever written by this DPP, lane 0 keeps its initial
// BIG forever (no per-slot re-init needed). Then e = min3(left,up,diag) + w.
#define CM2(W, XW, XS) \
    "v_mov_b32_dpp " XW ", %[e] wave_shr:1 row_mask:0xf bank_mask:0xf\n\t" \
    "v_min3_f32 %[tp], " XW ", %[e], " XS "\n\t" \
    "v_add_f32 %[e], %[tp], " W "\n\t"

// One waitcnt per TWO slots: 12 ds_reads outstanding; lgkmcnt(10) retires the
// two oldest (in-order DS), covering both slots' consumed w regs.
#define PAIR(WiA, WcA, WiB, WcB, XN, XO) \
    "s_waitcnt lgkmcnt(10)\n\t" \
    RD2(WiA) CM2(WcA, XN, XO) \
    RD2(WiB) CM2(WcB, XO, XN)

// One asm statement = 14 DP slots (7 pairs); slot issues the read for diag
// k+12 into w[(s+12)%14] and consumes w[s%14]; x0/x1 alternate per slot.
#define BODY14 \
    asm volatile( \
        PAIR("%[w13]", "%[w1]",  "%[w0]",  "%[w2]",  "%[x0]", "%[x1]") \
        PAIR("%[w1]",  "%[w3]",  "%[w2]",  "%[w4]",  "%[x0]", "%[x1]") \
        PAIR("%[w3]",  "%[w5]",  "%[w4]",  "%[w6]",  "%[x0]", "%[x1]") \
        PAIR("%[w5]",  "%[w7]",  "%[w6]",  "%[w8]",  "%[x0]", "%[x1]") \
        PAIR("%[w7]",  "%[w9]",  "%[w8]",  "%[w10]", "%[x0]", "%[x1]") \
        PAIR("%[w9]",  "%[w11]", "%[w10]", "%[w12]", "%[x0]", "%[x1]") \
        PAIR("%[w11]", "%[w13]", "%[w12]", "%[w0]",  "%[x0]", "%[x1]") \
        : [e]"+v"(e), [x0]"+v"(x0), [x1]"+v"(x1), [tp]"+v"(tp), \
          [au]"+v"(au), [ad]"+v"(ad), \
          [w0]"+v"(w0), [w1]"+v"(w1), [w2]"+v"(w2), [w3]"+v"(w3), \
          [w4]"+v"(w4), [w5]"+v"(w5), [w6]"+v"(w6), [w7]"+v"(w7), \
          [w8]"+v"(w8), [w9]"+v"(w9), [w10]"+v"(w10), [w11]"+v"(w11), \
          [w12]"+v"(w12), [w13]"+v"(w13) \
        : [sb]"v"(sb), [hi]"v"(hi) \
        : "memory")

// One 64-lane wave per sample; lane j owns column j; anti-diagonal sweep with
// potential transform e[v] = d[v] + img[v]/2:
//   e[v] = img[v] + min3(e_left, e_up, e_diag);  out = e_final - img[63][63]/2.
// Staging: 16x global_load_lds dwordx4 (direct HBM->LDS), gated into the DP
// with counted s_waitcnt vmcnt(N) so compute overlaps the ~12.5 us read phase
// (reads run at the empirically achievable ~2.7 TB/s device read rate).
__global__ __launch_bounds__(128) void dp_diag_kernel(const float* __restrict__ img,
                                                      float* __restrict__ out, int B) {
    __shared__ __align__(16) float smem[2][4096];   // 16 KB per wave, wave-private
    const int lane = threadIdx.x & 63;
    const int wave = threadIdx.x >> 6;
    const int b = (blockIdx.x << 1) + wave;
    if (b >= B) return;                // uniform per wave; no block barrier used

    float* s = smem[wave];
    {   // async staging: chunk t = rows 4t..4t+3; lane covers 16 B at lane*4 floats
        const float* g = img + ((size_t)b << 12) + (lane << 2);
        #pragma unroll
        for (int t = 0; t < 16; ++t)
            __builtin_amdgcn_global_load_lds(
                (const __attribute__((address_space(1))) void*)(g + (t << 8)),
                (__attribute__((address_space(3))) void*)(s + (t << 8)),
                16, 0, 0);
    }
    asm volatile("s_waitcnt vmcnt(12)\n\t" ::: "memory");  // t=0..3 done: rows 0..15

    float e  = (lane == 0) ? 0.5f * s[0] : BIG;   // diag k=0 state
    float x0 = BIG, x1 = BIG;   // written ONLY by lane-0-preserving DPP => lane0 stays BIG
    float w0 = 0, w1 = 0, w2 = 0, w3 = 0, w4 = 0, w5 = 0, w6 = 0,
          w7 = 0, w8 = 0, w9 = 0, w10 = 0, w11 = 0, w12 = 0, w13 = 0;
    float tp = 0;
    const int sb = (int)(unsigned)(uintptr_t)s + (lane << 2);  // row-0 byte addr
    const int hi = sb + 16128;                                 // row-63 byte addr
    int au = sb - (lane << 8);   // unclamped addr for diag 0 (pre-increment)
    int ad = 0;

    // prologue: issue ds_reads for diagonals k = 1..12 (rows <= 12) into w1..w12
    asm volatile(
        RD2("%[w1]") RD2("%[w2]") RD2("%[w3]") RD2("%[w4]") RD2("%[w5]") RD2("%[w6]")
        RD2("%[w7]") RD2("%[w8]") RD2("%[w9]") RD2("%[w10]") RD2("%[w11]") RD2("%[w12]")
        "s_nop 2\n\t"
        : [au]"+v"(au), [ad]"+v"(ad),
          [w1]"+v"(w1), [w2]"+v"(w2), [w3]"+v"(w3), [w4]"+v"(w4),
          [w5]"+v"(w5), [w6]"+v"(w6), [w7]"+v"(w7), [w8]"+v"(w8),
          [w9]"+v"(w9), [w10]"+v"(w10), [w11]"+v"(w11), [w12]"+v"(w12)
        : [sb]"v"(sb), [hi]"v"(hi)
        : "memory");

    // body blocks gated on staging progress (block issues reads up to row k0+25):
    asm volatile("s_waitcnt vmcnt(9)\n\t" ::: "memory");  // rows<=27 resident
    BODY14;                                               // k = 1..14
    asm volatile("s_waitcnt vmcnt(5)\n\t" ::: "memory");  // rows<=43 resident
    BODY14;                                               // k = 15..28
    asm volatile("s_waitcnt vmcnt(2)\n\t" ::: "memory");  // rows<=55 resident
    BODY14;                                               // k = 29..42
    asm volatile("s_waitcnt vmcnt(0)\n\t" ::: "memory");  // all rows resident
    BODY14;                                               // k = 43..56
    #pragma unroll 1
    for (int it = 0; it < 5; ++it)                        // k = 57..126
        BODY14;
    asm volatile("s_waitcnt lgkmcnt(0)\n\t" ::: "memory"); // drain 12 dangling reads

    if (lane == 63) out[b] = e - 0.5f * s[4095];  // d[63][63]
}

extern "C" void kernel_launch(void* const* d_in, const int* in_sizes, int n_in,
                              void* d_out, int out_size, void* d_ws, size_t ws_size,
                              hipStream_t stream) {
    const float* img = (const float*)d_in[0];
    float* out = (float*)d_out;
    const int B = out_size;                  // 2048
    const int threads = 128;                 // 2 waves (samples) per block
    const int grid = (B + 1) / 2;
    dp_diag_kernel<<<grid, threads, 0, stream>>>(img, out, B);
}